// Round 1
// 322.890 us; speedup vs baseline: 1.0671x; 1.0671x over previous
//
#include <hip/hip_runtime.h>
#include <math.h>

// Problem constants
#define BB 512
#define TT 2048
#define AA 16
#define NTOT (512LL * 2048LL * 16LL)   // 16,777,216
#define GAMMA 0.99f
#define GLAM  0.9405f                  // gamma * lam, matches python double->f32
#define ENTC  1.4189385332046727f      // 0.5 + 0.5*log(2*pi)

#define NB2 2048                       // blocks for obj kernel
#define NB3 2048                       // blocks for out kernel

typedef float f32x4 __attribute__((ext_vector_type(4)));

// ---------------------------------------------------------------------------
// K1: GAE via parallel affine scan. One block (256 threads) per batch row.
// Reversed recurrence y_u = a_u * y_{u-1} + b_u with u = T-1-t:
//   u==0: (a,b)=(0,0)  -> adv[T-1]=0
//   u>=1: t=T-1-u, b=td[t]=r[t]+g*V[t+1]-V[t], a=g*lam*(1-done[t+1])
// Per-thread data is 8 CONSECUTIVE t (32B) per stream -> float4/int4 loads
// for rewards/dones (rows 16B-aligned); V rows have stride 2049 floats
// (misaligned), kept scalar. Block 0 also zeroes the f64 accumulator that
// obj_kernel's atomics target.
// ---------------------------------------------------------------------------
__global__ __launch_bounds__(256) void gae_kernel(
    const float* __restrict__ rewards, const float* __restrict__ vout,
    const int* __restrict__ dones, float* __restrict__ adv,
    double* __restrict__ total)
{
    const int b   = blockIdx.x;
    const int tid = threadIdx.x;
    if (b == 0 && tid == 0) *total = 0.0;   // reset accumulator each launch

    const float* rw = rewards + (size_t)b * TT;
    const float* V  = vout    + (size_t)b * (TT + 1);
    const int*   dn = dones   + (size_t)b * TT;
    float*       av = adv     + (size_t)b * TT;

    const int t_lo = TT - 8 - 8 * tid;      // multiple of 8 -> 32B aligned

    // vector loads where alignment allows
    float4 rA = *(const float4*)(rw + t_lo);
    float4 rB = *(const float4*)(rw + t_lo + 4);
    int4   dA = *(const int4*)(dn + t_lo);
    int4   dB = *(const int4*)(dn + t_lo + 4);
    int    d8 = (tid == 0) ? 1 : dn[t_lo + 8];   // dn[2048] would be OOB for tid 0; value unused there
    float vv[9];
    #pragma unroll
    for (int j = 0; j < 9; ++j) vv[j] = V[t_lo + j];   // V[t_lo+8] = V[2048] is valid (T+1 cols)

    float rr[8] = {rA.x, rA.y, rA.z, rA.w, rB.x, rB.y, rB.z, rB.w};
    int   dd[9] = {dA.x, dA.y, dA.z, dA.w, dB.x, dB.y, dB.z, dB.w, d8};

    float ak[8], bk[8];
    float SA = 1.f, SB = 0.f;   // segment composite (applied earliest-first)
    #pragma unroll
    for (int k = 0; k < 8; ++k) {
        // u = tid*8 + k ; t = TT-1-u = t_lo + (7-k)
        const int j = 7 - k;
        float bu = rr[j] + GAMMA * vv[j + 1] - vv[j];
        float au = GLAM * (1.f - (float)dd[j + 1]);
        if (k == 0 && tid == 0) { au = 0.f; bu = 0.f; }   // u == 0
        ak[k] = au; bk[k] = bu;
        SB = au * SB + bu;    // compose f_u after current composite
        SA = au * SA;
    }

    const int lane = tid & 63;
    const int wave = tid >> 6;

    // wave-inclusive scan of composites; compose(me, prev): B=A_me*B_prev+B_me
    #pragma unroll
    for (int off = 1; off < 64; off <<= 1) {
        float pA = __shfl_up(SA, off, 64);
        float pB = __shfl_up(SB, off, 64);
        if (lane >= off) { SB = SA * pB + SB; SA = SA * pA; }
    }

    __shared__ float wA[4], wB[4];
    if (lane == 63) { wA[wave] = SA; wB[wave] = SB; }
    __syncthreads();

    // composite of all waves before mine (identity for wave 0)
    float PA = 1.f, PB = 0.f;
    for (int w = 0; w < wave; ++w) {
        float aw = wA[w], bw = wB[w];
        PB = aw * PB + bw;
        PA = aw * PA;
    }

    // exclusive within wave
    float EA = __shfl_up(SA, 1, 64);
    float EB = __shfl_up(SB, 1, 64);
    if (lane == 0) { EA = 1.f; EB = 0.f; }

    // carry into my segment = (E ∘ P)(0) = EA*PB + EB
    float x = EA * PB + EB;
    float outb[8];
    #pragma unroll
    for (int k = 0; k < 8; ++k) {
        x = ak[k] * x + bk[k];
        outb[7 - k] = x;           // store at t = t_lo + (7-k)
    }
    *(float4*)(av + t_lo)     = make_float4(outb[0], outb[1], outb[2], outb[3]);
    *(float4*)(av + t_lo + 4) = make_float4(outb[4], outb[5], outb[6], outb[7]);
}

// ---------------------------------------------------------------------------
// K2: PPO objective partial sums. clipped == 0.8 (faithful clip bug).
// obj = min(adv*ratio, adv*0.8), ratio = (os/s)*exp(0.5*(zo^2 - z^2)).
// Explicit depth-2 software pipeline: issue iteration i+1's 6 loads, then
// compute iteration i -> ~6KB outstanding per wave (the previous version's
// VGPR_Count=28 shows the compiler kept ~1 load in flight; that is the
// 2.9 TB/s MLP wall). Single-use streams are nontemporal so sigma stays
// resident in L3 for out_kernel. Block sum -> device-scope f64 atomic.
// ---------------------------------------------------------------------------
__device__ __forceinline__ float obj1(float x, float m, float s,
                                      float om, float os, float ad)
{
    float rs  = __builtin_amdgcn_rcpf(s);
    float ros = __builtin_amdgcn_rcpf(os);
    float z   = (x - m) * rs;
    float zo  = (x - om) * ros;
    float d   = 0.5f * (zo * zo - z * z);
    float ratio = os * rs * __expf(d);
    return fminf(ad * ratio, ad * 0.8f);
}

__device__ __forceinline__ double obj4d(f32x4 m, f32x4 s, f32x4 om, f32x4 os,
                                        f32x4 x, float ad)
{
    float o0 = obj1(x.x, m.x, s.x, om.x, os.x, ad);
    float o1 = obj1(x.y, m.y, s.y, om.y, os.y, ad);
    float o2 = obj1(x.z, m.z, s.z, om.z, os.z, ad);
    float o3 = obj1(x.w, m.w, s.w, om.w, os.w, ad);
    return (double)o0 + (double)o1 + (double)o2 + (double)o3;
}

__global__ __launch_bounds__(256) void obj_kernel(
    const float* __restrict__ mu, const float* __restrict__ sigma,
    const float* __restrict__ old_mu, const float* __restrict__ old_sigma,
    const float* __restrict__ actions, const float* __restrict__ adv,
    double* __restrict__ total)
{
    const int tid = threadIdx.x;
    uint32_t v = (uint32_t)blockIdx.x * 256u + (uint32_t)tid;   // float4 index
    const uint32_t stride = (uint32_t)NB2 * 256u;

    const f32x4* m4  = (const f32x4*)mu;
    const f32x4* s4  = (const f32x4*)sigma;
    const f32x4* om4 = (const f32x4*)old_mu;
    const f32x4* os4 = (const f32x4*)old_sigma;
    const f32x4* x4  = (const f32x4*)actions;

    // prologue: iteration 0 loads
    f32x4 m0  = __builtin_nontemporal_load(m4 + v);
    f32x4 s0  = s4[v];                                   // keep sigma cached for out_kernel
    f32x4 om0 = __builtin_nontemporal_load(om4 + v);
    f32x4 os0 = __builtin_nontemporal_load(os4 + v);
    f32x4 x0  = __builtin_nontemporal_load(x4 + v);
    float a0  = adv[v >> 2];

    double lsum = 0.0;
    #pragma unroll 1
    for (int it = 0; it < 7; ++it) {
        const uint32_t w = v + stride;
        // issue next iteration's loads before computing the current one
        f32x4 m1  = __builtin_nontemporal_load(m4 + w);
        f32x4 s1  = s4[w];
        f32x4 om1 = __builtin_nontemporal_load(om4 + w);
        f32x4 os1 = __builtin_nontemporal_load(os4 + w);
        f32x4 x1  = __builtin_nontemporal_load(x4 + w);
        float a1  = adv[w >> 2];

        lsum += obj4d(m0, s0, om0, os0, x0, a0);

        m0 = m1; s0 = s1; om0 = om1; os0 = os1; x0 = x1; a0 = a1; v = w;
    }
    lsum += obj4d(m0, s0, om0, os0, x0, a0);

    // wave reduce (f64 shuffle)
    #pragma unroll
    for (int off = 32; off > 0; off >>= 1)
        lsum += __shfl_down(lsum, off, 64);

    __shared__ double wsum[4];
    const int lane = tid & 63, wave = tid >> 6;
    if (lane == 0) wsum[wave] = lsum;
    __syncthreads();
    if (tid == 0) {
        double bsum = wsum[0] + wsum[1] + wsum[2] + wsum[3];
        __hip_atomic_fetch_add(total, bsum, __ATOMIC_RELAXED,
                               __HIP_MEMORY_SCOPE_AGENT);
    }
}

// ---------------------------------------------------------------------------
// K3: out[i] = mean + log(sigma[i]) + 0.5 + 0.5*log(2*pi)
// Grid-stride, depth-2 pipelined loads, nontemporal stores.
// ---------------------------------------------------------------------------
__global__ __launch_bounds__(256) void out_kernel(
    const float* __restrict__ sigma, const double* __restrict__ total,
    float* __restrict__ out)
{
    const int tid = threadIdx.x;
    const float mean = (float)(*total / (double)NTOT);

    uint32_t v = (uint32_t)blockIdx.x * 256u + (uint32_t)tid;   // float4 index
    const uint32_t stride = (uint32_t)NB3 * 256u;
    const f32x4* s4 = (const f32x4*)sigma;
    f32x4* o4 = (f32x4*)out;

    f32x4 s0 = s4[v];
    #pragma unroll 1
    for (int it = 0; it < 7; ++it) {
        const uint32_t w = v + stride;
        f32x4 s1 = s4[w];
        f32x4 o;
        o.x = mean + __logf(s0.x) + ENTC;
        o.y = mean + __logf(s0.y) + ENTC;
        o.z = mean + __logf(s0.z) + ENTC;
        o.w = mean + __logf(s0.w) + ENTC;
        __builtin_nontemporal_store(o, o4 + v);
        s0 = s1; v = w;
    }
    f32x4 o;
    o.x = mean + __logf(s0.x) + ENTC;
    o.y = mean + __logf(s0.y) + ENTC;
    o.z = mean + __logf(s0.z) + ENTC;
    o.w = mean + __logf(s0.w) + ENTC;
    __builtin_nontemporal_store(o, o4 + v);
}

// ---------------------------------------------------------------------------
extern "C" void kernel_launch(void* const* d_in, const int* in_sizes, int n_in,
                              void* d_out, int out_size, void* d_ws, size_t ws_size,
                              hipStream_t stream) {
    const float* rewards   = (const float*)d_in[0];   // [B,T]
    const float* critic    = (const float*)d_in[1];   // [B,T+1]
    const float* mu        = (const float*)d_in[2];   // [B,T,A]
    const float* sigma     = (const float*)d_in[3];
    const float* old_mu    = (const float*)d_in[4];
    const float* old_sigma = (const float*)d_in[5];
    const float* actions   = (const float*)d_in[6];
    const int*   dones     = (const int*)d_in[7];     // [B,T]
    float* out = (float*)d_out;

    char* ws = (char*)d_ws;
    double* total = (double*)ws;                      // 8 B accumulator
    float*  adv   = (float*)(ws + 32768);             // 4 MB (B*T floats)

    gae_kernel<<<BB, 256, 0, stream>>>(rewards, critic, dones, adv, total);
    obj_kernel<<<NB2, 256, 0, stream>>>(mu, sigma, old_mu, old_sigma,
                                        actions, adv, total);
    out_kernel<<<NB3, 256, 0, stream>>>(sigma, total, out);
}